// Round 1
// baseline (2994.708 us; speedup 1.0000x reference)
//
#include <hip/hip_runtime.h>

#define B_ 4
#define N_ 1024
#define D_ 1024
#define H_ 16
#define HD_ 64
#define E_ 12
#define T_ 4096
#define FF_ 4096

static constexpr size_t SZ_ = (size_t)T_ * D_;

__device__ __forceinline__ float wave_sum64(float v) {
#pragma unroll
  for (int o = 32; o > 0; o >>= 1) v += __shfl_down(v, o);
  return v;
}

__device__ __forceinline__ float gelu_f(float x) {
  // jax.nn.gelu approximate=True (tanh form)
  float u = 0.7978845608028654f * (x + 0.044715f * x * x * x);
  u = fminf(fmaxf(u, -15.f), 15.f);
  float e = __expf(2.f * u);
  float th = (e - 1.f) / (e + 1.f);
  return 0.5f * x * (1.f + th);
}

// ---------------- LayerNorm (one block per token, 256 thr, D=1024) ----------
__global__ __launch_bounds__(256) void ln_kernel(const float* __restrict__ x,
    const float* __restrict__ g, const float* __restrict__ b,
    float* __restrict__ out) {
  const int t = blockIdx.x, tid = threadIdx.x;
  const size_t base = (size_t)t * D_;
  const float4 v = ((const float4*)(x + base))[tid];
  float s = v.x + v.y + v.z + v.w;
  float s2 = v.x * v.x + v.y * v.y + v.z * v.z + v.w * v.w;
  s = wave_sum64(s);
  s2 = wave_sum64(s2);
  __shared__ float ls[4], ls2[4];
  const int w = tid >> 6;
  if ((tid & 63) == 0) { ls[w] = s; ls2[w] = s2; }
  __syncthreads();
  const float mean = (ls[0] + ls[1] + ls[2] + ls[3]) * (1.0f / D_);
  const float var = (ls2[0] + ls2[1] + ls2[2] + ls2[3]) * (1.0f / D_) - mean * mean;
  const float inv = rsqrtf(var + 1e-5f);
  const float4 gg = ((const float4*)g)[tid];
  const float4 bb = ((const float4*)b)[tid];
  float4 o4;
  o4.x = (v.x - mean) * inv * gg.x + bb.x;
  o4.y = (v.y - mean) * inv * gg.y + bb.y;
  o4.z = (v.z - mean) * inv * gg.z + bb.z;
  o4.w = (v.w - mean) * inv * gg.w + bb.w;
  ((float4*)(out + base))[tid] = o4;
}

// -------- h = x + o0 + o1; hn = LN(h)  (fused residual + LN2) ---------------
__global__ __launch_bounds__(256) void hln2_kernel(const float* __restrict__ x,
    const float* __restrict__ oa, const float* __restrict__ ob,
    const float* __restrict__ g, const float* __restrict__ be,
    float* __restrict__ hout, float* __restrict__ hn) {
  const int t = blockIdx.x, tid = threadIdx.x;
  const size_t base = (size_t)t * D_;
  const float4 xv = ((const float4*)(x + base))[tid];
  const float4 av = ((const float4*)(oa + base))[tid];
  const float4 bv = ((const float4*)(ob + base))[tid];
  float4 hv;
  hv.x = xv.x + av.x + bv.x;
  hv.y = xv.y + av.y + bv.y;
  hv.z = xv.z + av.z + bv.z;
  hv.w = xv.w + av.w + bv.w;
  ((float4*)(hout + base))[tid] = hv;
  float s = hv.x + hv.y + hv.z + hv.w;
  float s2 = hv.x * hv.x + hv.y * hv.y + hv.z * hv.z + hv.w * hv.w;
  s = wave_sum64(s);
  s2 = wave_sum64(s2);
  __shared__ float ls[4], ls2[4];
  const int w = tid >> 6;
  if ((tid & 63) == 0) { ls[w] = s; ls2[w] = s2; }
  __syncthreads();
  const float mean = (ls[0] + ls[1] + ls[2] + ls[3]) * (1.0f / D_);
  const float var = (ls2[0] + ls2[1] + ls2[2] + ls2[3]) * (1.0f / D_) - mean * mean;
  const float inv = rsqrtf(var + 1e-5f);
  const float4 gg = ((const float4*)g)[tid];
  const float4 bb = ((const float4*)be)[tid];
  float4 o4;
  o4.x = (hv.x - mean) * inv * gg.x + bb.x;
  o4.y = (hv.y - mean) * inv * gg.y + bb.y;
  o4.z = (hv.z - mean) * inv * gg.z + bb.z;
  o4.w = (hv.w - mean) * inv * gg.w + bb.w;
  ((float4*)(hn + base))[tid] = o4;
}

// ---------------- Router: logits, softmax, top-2, expert lists --------------
__global__ __launch_bounds__(256) void router_kernel(const float* __restrict__ xn,
    const float* __restrict__ Wr, float* __restrict__ counts,
    float* __restrict__ psum, int* __restrict__ ecnt, int* __restrict__ etok,
    float* __restrict__ ewt) {
  const int t = blockIdx.x, tid = threadIdx.x;
  const float4 xv = ((const float4*)(xn + (size_t)t * D_))[tid];
  float acc[E_];
#pragma unroll
  for (int e = 0; e < E_; ++e) {
    const float4 wv = ((const float4*)(Wr + (size_t)e * D_))[tid];
    acc[e] = xv.x * wv.x + xv.y * wv.y + xv.z * wv.z + xv.w * wv.w;
  }
#pragma unroll
  for (int e = 0; e < E_; ++e) acc[e] = wave_sum64(acc[e]);
  __shared__ float red[4][E_];
  const int w = tid >> 6;
  if ((tid & 63) == 0) {
#pragma unroll
    for (int e = 0; e < E_; ++e) red[w][e] = acc[e];
  }
  __syncthreads();
  if (tid == 0) {
    float lg[E_];
    float mx = -1e30f;
#pragma unroll
    for (int e = 0; e < E_; ++e) {
      lg[e] = red[0][e] + red[1][e] + red[2][e] + red[3][e];
      mx = fmaxf(mx, lg[e]);
    }
    float p[E_];
    float sum = 0.f;
#pragma unroll
    for (int e = 0; e < E_; ++e) { p[e] = __expf(lg[e] - mx); sum += p[e]; }
    const float invs = 1.f / sum;
#pragma unroll
    for (int e = 0; e < E_; ++e) p[e] *= invs;
    int i0 = 0;
#pragma unroll
    for (int e = 1; e < E_; ++e) if (p[e] > p[i0]) i0 = e;
    int i1 = (i0 == 0) ? 1 : 0;
#pragma unroll
    for (int e = 0; e < E_; ++e) if (e != i0 && p[e] > p[i1]) i1 = e;
    const float rs = 1.f / (p[i0] + p[i1] + 1e-6f);
    const float w0 = p[i0] * rs, w1 = p[i1] * rs;
    atomicAdd(&counts[i0], 1.f);
    atomicAdd(&counts[i1], 1.f);
#pragma unroll
    for (int e = 0; e < E_; ++e) atomicAdd(&psum[e], p[e]);
    int p0 = atomicAdd(&ecnt[i0], 1);
    etok[i0 * T_ + p0] = t;            // slot kk=0
    ewt[i0 * T_ + p0] = w0;
    int p1 = atomicAdd(&ecnt[i1], 1);
    etok[i1 * T_ + p1] = t | (1 << 16);  // slot kk=1
    ewt[i1 * T_ + p1] = w1;
  }
}

// ------- Gathered per-expert GEMM: out[kk*kkStride + tok*D + n] = w*(xn@We.T)
__global__ __launch_bounds__(256) void moe_gemm(const float* __restrict__ in,
    const float* __restrict__ Wall, float* __restrict__ out, size_t kkStride,
    const int* __restrict__ ecnt, const int* __restrict__ etok,
    const float* __restrict__ ewt) {
  const int e = blockIdx.z;
  const int Me = ecnt[e];
  const int m0 = blockIdx.y * 64;
  if (m0 >= Me) return;
  const int n0 = blockIdx.x * 64;
  const float* W = Wall + (size_t)e * D_ * D_;
  __shared__ __align__(16) float As[16][68];
  __shared__ __align__(16) float Bs[16][68];
  __shared__ int stok[64];
  __shared__ float swt[64];
  const int tid = threadIdx.x;
  if (tid < 64) {
    const int s = m0 + tid;
    if (s < Me) { stok[tid] = etok[e * T_ + s]; swt[tid] = ewt[e * T_ + s]; }
    else        { stok[tid] = 0;                swt[tid] = 0.f; }
  }
  __syncthreads();
  const int lm = tid >> 2;
  const int lk = (tid & 3) * 4;
  const int tx = tid & 15, ty = tid >> 4;
  const float* arow = in + (size_t)(stok[lm] & 0xFFFF) * D_ + lk;
  const float* brow = W + (size_t)(n0 + lm) * D_ + lk;
  float acc[4][4] = {};
  for (int kt = 0; kt < D_; kt += 16) {
    const float4 a4 = *(const float4*)(arow + kt);
    const float4 b4 = *(const float4*)(brow + kt);
    As[lk + 0][lm] = a4.x; As[lk + 1][lm] = a4.y;
    As[lk + 2][lm] = a4.z; As[lk + 3][lm] = a4.w;
    Bs[lk + 0][lm] = b4.x; Bs[lk + 1][lm] = b4.y;
    Bs[lk + 2][lm] = b4.z; Bs[lk + 3][lm] = b4.w;
    __syncthreads();
#pragma unroll
    for (int kk = 0; kk < 16; ++kk) {
      const float4 av = *(const float4*)&As[kk][ty * 4];
      const float4 bv = *(const float4*)&Bs[kk][tx * 4];
      const float a_[4] = {av.x, av.y, av.z, av.w};
      const float b_[4] = {bv.x, bv.y, bv.z, bv.w};
#pragma unroll
      for (int i = 0; i < 4; ++i)
#pragma unroll
        for (int j = 0; j < 4; ++j) acc[i][j] = fmaf(a_[i], b_[j], acc[i][j]);
    }
    __syncthreads();
  }
#pragma unroll
  for (int i = 0; i < 4; ++i) {
    const int srow = ty * 4 + i;
    if (m0 + srow < Me) {
      const int pk = stok[srow];
      const int tok = pk & 0xFFFF;
      const size_t kk = (size_t)(pk >> 16);
      const float wv = swt[srow];
      float4 r;
      r.x = acc[i][0] * wv; r.y = acc[i][1] * wv;
      r.z = acc[i][2] * wv; r.w = acc[i][3] * wv;
      *(float4*)(out + kk * kkStride + (size_t)tok * D_ + n0 + tx * 4) = r;
    }
  }
}

// ---------------- in-place a += b (float4) ----------------------------------
__global__ __launch_bounds__(256) void add2_kernel(float* __restrict__ a,
                                                   const float* __restrict__ b) {
  const size_t i = (size_t)blockIdx.x * 256 + threadIdx.x;
  float4 x = ((float4*)a)[i];
  const float4 yv = ((const float4*)b)[i];
  x.x += yv.x; x.y += yv.y; x.z += yv.z; x.w += yv.w;
  ((float4*)a)[i] = x;
}

// ---------------- Flash attention, 64-row q tile per block ------------------
__global__ __launch_bounds__(256) void attn_kernel(const float* __restrict__ q,
    const float* __restrict__ k, const float* __restrict__ v,
    float* __restrict__ out) {
  const int bh = blockIdx.x;
  const int b = bh >> 4, h = bh & 15;
  const int q0 = blockIdx.y * 64;
  const int tid = threadIdx.x;
  const int tx = tid & 15, ty = tid >> 4;
  __shared__ __align__(16) float Qs[64][64];  // [d][r]
  __shared__ __align__(16) float Ks[64][64];  // [d][c]
  __shared__ __align__(16) float Vs[64][64];  // [kv][c]
  __shared__ __align__(16) float Ps[64][64];  // [r][c]
  {
    const int r = tid >> 2, d0 = (tid & 3) * 16;
    const float* src = q + ((size_t)(b * N_ + q0 + r)) * D_ + h * HD_ + d0;
#pragma unroll
    for (int j = 0; j < 16; j += 4) {
      const float4 t4 = *(const float4*)(src + j);
      Qs[d0 + j + 0][r] = t4.x * 0.125f;
      Qs[d0 + j + 1][r] = t4.y * 0.125f;
      Qs[d0 + j + 2][r] = t4.z * 0.125f;
      Qs[d0 + j + 3][r] = t4.w * 0.125f;
    }
  }
  float m_i[4], l_i[4], o_acc[4][4];
#pragma unroll
  for (int i = 0; i < 4; ++i) {
    m_i[i] = -3.0e38f;
    l_i[i] = 0.f;
#pragma unroll
    for (int j = 0; j < 4; ++j) o_acc[i][j] = 0.f;
  }
  for (int kt = 0; kt < 16; ++kt) {
    __syncthreads();  // Q ready (kt=0) / prev PV done before K,V overwrite
    {
      const int r = tid >> 2, d0 = (tid & 3) * 16;
      const float* ks = k + ((size_t)(b * N_ + kt * 64 + r)) * D_ + h * HD_ + d0;
      const float* vs = v + ((size_t)(b * N_ + kt * 64 + r)) * D_ + h * HD_ + d0;
#pragma unroll
      for (int j = 0; j < 16; j += 4) {
        const float4 t4 = *(const float4*)(ks + j);
        Ks[d0 + j + 0][r] = t4.x; Ks[d0 + j + 1][r] = t4.y;
        Ks[d0 + j + 2][r] = t4.z; Ks[d0 + j + 3][r] = t4.w;
        const float4 u4 = *(const float4*)(vs + j);
        *(float4*)&Vs[r][d0 + j] = u4;
      }
    }
    __syncthreads();
    float s[4][4] = {};
#pragma unroll 8
    for (int d = 0; d < 64; ++d) {
      const float4 av = *(const float4*)&Qs[d][ty * 4];
      const float4 bv = *(const float4*)&Ks[d][tx * 4];
      const float a_[4] = {av.x, av.y, av.z, av.w};
      const float b_[4] = {bv.x, bv.y, bv.z, bv.w};
#pragma unroll
      for (int i = 0; i < 4; ++i)
#pragma unroll
        for (int j = 0; j < 4; ++j) s[i][j] = fmaf(a_[i], b_[j], s[i][j]);
    }
    float alpha[4];
#pragma unroll
    for (int i = 0; i < 4; ++i) {
      float mt = fmaxf(fmaxf(s[i][0], s[i][1]), fmaxf(s[i][2], s[i][3]));
#pragma unroll
      for (int o = 8; o > 0; o >>= 1) mt = fmaxf(mt, __shfl_xor(mt, o));
      const float mn = fmaxf(m_i[i], mt);
      alpha[i] = __expf(m_i[i] - mn);
      m_i[i] = mn;
      float rsum = 0.f;
#pragma unroll
      for (int j = 0; j < 4; ++j) { s[i][j] = __expf(s[i][j] - mn); rsum += s[i][j]; }
#pragma unroll
      for (int o = 8; o > 0; o >>= 1) rsum += __shfl_xor(rsum, o);
      l_i[i] = l_i[i] * alpha[i] + rsum;
      Ps[ty * 4 + i][tx * 4 + 0] = s[i][0];
      Ps[ty * 4 + i][tx * 4 + 1] = s[i][1];
      Ps[ty * 4 + i][tx * 4 + 2] = s[i][2];
      Ps[ty * 4 + i][tx * 4 + 3] = s[i][3];
    }
    __syncthreads();
#pragma unroll
    for (int i = 0; i < 4; ++i)
#pragma unroll
      for (int j = 0; j < 4; ++j) o_acc[i][j] *= alpha[i];
#pragma unroll 8
    for (int d = 0; d < 64; ++d) {
      const float4 vv = *(const float4*)&Vs[d][tx * 4];
      const float v_[4] = {vv.x, vv.y, vv.z, vv.w};
      const float p0 = Ps[ty * 4 + 0][d];
      const float p1 = Ps[ty * 4 + 1][d];
      const float p2 = Ps[ty * 4 + 2][d];
      const float p3 = Ps[ty * 4 + 3][d];
#pragma unroll
      for (int j = 0; j < 4; ++j) {
        o_acc[0][j] = fmaf(p0, v_[j], o_acc[0][j]);
        o_acc[1][j] = fmaf(p1, v_[j], o_acc[1][j]);
        o_acc[2][j] = fmaf(p2, v_[j], o_acc[2][j]);
        o_acc[3][j] = fmaf(p3, v_[j], o_acc[3][j]);
      }
    }
  }
#pragma unroll
  for (int i = 0; i < 4; ++i) {
    const float inv = 1.f / l_i[i];
    float4 o4;
    o4.x = o_acc[i][0] * inv; o4.y = o_acc[i][1] * inv;
    o4.z = o_acc[i][2] * inv; o4.w = o_acc[i][3] * inv;
    *(float4*)(out + ((size_t)(b * N_ + q0 + ty * 4 + i)) * D_ + h * HD_ + tx * 4) = o4;
  }
}

// ---------------- FFN GEMM 1: mid = gelu(hn2 @ W1.T + b1) -------------------
__global__ __launch_bounds__(256) void ffn1_kernel(const float* __restrict__ A,
    const float* __restrict__ W, const float* __restrict__ bias,
    float* __restrict__ mid) {
  const int m0 = blockIdx.y * 64, n0 = blockIdx.x * 64;
  __shared__ __align__(16) float As[16][68];
  __shared__ __align__(16) float Bs[16][68];
  const int tid = threadIdx.x;
  const int lm = tid >> 2, lk = (tid & 3) * 4;
  const int tx = tid & 15, ty = tid >> 4;
  const float* arow = A + (size_t)(m0 + lm) * D_ + lk;
  const float* brow = W + (size_t)(n0 + lm) * D_ + lk;
  float acc[4][4] = {};
  for (int kt = 0; kt < D_; kt += 16) {
    const float4 a4 = *(const float4*)(arow + kt);
    const float4 b4 = *(const float4*)(brow + kt);
    As[lk + 0][lm] = a4.x; As[lk + 1][lm] = a4.y;
    As[lk + 2][lm] = a4.z; As[lk + 3][lm] = a4.w;
    Bs[lk + 0][lm] = b4.x; Bs[lk + 1][lm] = b4.y;
    Bs[lk + 2][lm] = b4.z; Bs[lk + 3][lm] = b4.w;
    __syncthreads();
#pragma unroll
    for (int kk = 0; kk < 16; ++kk) {
      const float4 av = *(const float4*)&As[kk][ty * 4];
      const float4 bv = *(const float4*)&Bs[kk][tx * 4];
      const float a_[4] = {av.x, av.y, av.z, av.w};
      const float b_[4] = {bv.x, bv.y, bv.z, bv.w};
#pragma unroll
      for (int i = 0; i < 4; ++i)
#pragma unroll
        for (int j = 0; j < 4; ++j) acc[i][j] = fmaf(a_[i], b_[j], acc[i][j]);
    }
    __syncthreads();
  }
  const float4 bv4 = *(const float4*)(bias + n0 + tx * 4);
  const float bb[4] = {bv4.x, bv4.y, bv4.z, bv4.w};
#pragma unroll
  for (int i = 0; i < 4; ++i) {
    float4 r;
    r.x = gelu_f(acc[i][0] + bb[0]);
    r.y = gelu_f(acc[i][1] + bb[1]);
    r.z = gelu_f(acc[i][2] + bb[2]);
    r.w = gelu_f(acc[i][3] + bb[3]);
    *(float4*)(mid + (size_t)(m0 + ty * 4 + i) * FF_ + n0 + tx * 4) = r;
  }
}

// ------------- FFN GEMM 2: y = h + mid @ W2.T + b2 --------------------------
__global__ __launch_bounds__(256) void ffn2_kernel(const float* __restrict__ A,
    const float* __restrict__ W, const float* __restrict__ bias,
    const float* __restrict__ hres, float* __restrict__ y) {
  const int m0 = blockIdx.y * 64, n0 = blockIdx.x * 64;
  __shared__ __align__(16) float As[16][68];
  __shared__ __align__(16) float Bs[16][68];
  const int tid = threadIdx.x;
  const int lm = tid >> 2, lk = (tid & 3) * 4;
  const int tx = tid & 15, ty = tid >> 4;
  const float* arow = A + (size_t)(m0 + lm) * FF_ + lk;
  const float* brow = W + (size_t)(n0 + lm) * FF_ + lk;
  float acc[4][4] = {};
  for (int kt = 0; kt < FF_; kt += 16) {
    const float4 a4 = *(const float4*)(arow + kt);
    const float4 b4 = *(const float4*)(brow + kt);
    As[lk + 0][lm] = a4.x; As[lk + 1][lm] = a4.y;
    As[lk + 2][lm] = a4.z; As[lk + 3][lm] = a4.w;
    Bs[lk + 0][lm] = b4.x; Bs[lk + 1][lm] = b4.y;
    Bs[lk + 2][lm] = b4.z; Bs[lk + 3][lm] = b4.w;
    __syncthreads();
#pragma unroll
    for (int kk = 0; kk < 16; ++kk) {
      const float4 av = *(const float4*)&As[kk][ty * 4];
      const float4 bv = *(const float4*)&Bs[kk][tx * 4];
      const float a_[4] = {av.x, av.y, av.z, av.w};
      const float b_[4] = {bv.x, bv.y, bv.z, bv.w};
#pragma unroll
      for (int i = 0; i < 4; ++i)
#pragma unroll
        for (int j = 0; j < 4; ++j) acc[i][j] = fmaf(a_[i], b_[j], acc[i][j]);
    }
    __syncthreads();
  }
  const float4 bv4 = *(const float4*)(bias + n0 + tx * 4);
  const float bb[4] = {bv4.x, bv4.y, bv4.z, bv4.w};
#pragma unroll
  for (int i = 0; i < 4; ++i) {
    const int row = m0 + ty * 4 + i;
    const float4 hv = *(const float4*)(hres + (size_t)row * D_ + n0 + tx * 4);
    float4 r;
    r.x = acc[i][0] + bb[0] + hv.x;
    r.y = acc[i][1] + bb[1] + hv.y;
    r.z = acc[i][2] + bb[2] + hv.z;
    r.w = acc[i][3] + bb[3] + hv.w;
    *(float4*)(y + (size_t)row * D_ + n0 + tx * 4) = r;
  }
}

// ---------------- load-balance scalar ---------------------------------------
__global__ void lb_kernel(const float* __restrict__ counts,
                          const float* __restrict__ psum, float* __restrict__ out) {
  if (threadIdx.x == 0 && blockIdx.x == 0) {
    float tot = 0.f;
    for (int e = 0; e < E_; ++e) tot += counts[e];
    float s = 0.f;
    for (int e = 0; e < E_; ++e) s += counts[e] / (tot + 1e-6f) * psum[e];
    out[0] = s * (float)E_;
  }
}

extern "C" void kernel_launch(void* const* d_in, const int* in_sizes, int n_in,
                              void* d_out, int out_size, void* d_ws, size_t ws_size,
                              hipStream_t stream) {
  (void)in_sizes; (void)n_in; (void)out_size; (void)ws_size;
  const float* x  = (const float*)d_in[0];
  const float* Wr = (const float*)d_in[1];
  const float* Wq = (const float*)d_in[2];
  const float* Wk = (const float*)d_in[3];
  const float* Wv = (const float*)d_in[4];
  const float* Wo = (const float*)d_in[5];
  const float* W1 = (const float*)d_in[6];
  const float* b1 = (const float*)d_in[7];
  const float* W2 = (const float*)d_in[8];
  const float* b2 = (const float*)d_in[9];
  const float* g1 = (const float*)d_in[10];
  const float* be1 = (const float*)d_in[11];
  const float* g2 = (const float*)d_in[12];
  const float* be2 = (const float*)d_in[13];
  float* y = (float*)d_out;
  float* ws = (float*)d_ws;

  // workspace slots (each SZ_ = T*D floats = 16 MB)
  float* xn   = ws + 0 * SZ_;  // later: attn_out, then hn2
  float* q2   = ws + 1 * SZ_;  // [2][T][D]; combined q in first half; later mid
  float* k2   = ws + 3 * SZ_;  // [2][T][D]
  float* v2   = ws + 5 * SZ_;  // [2][T][D]
  float* o2a  = ws + 2 * SZ_;  // o slot 0 (q2[1] slot, dead by then)
  float* o2b  = ws + 4 * SZ_;  // o slot 1 (k2[1] slot, dead by then)
  float* hbuf = ws + 6 * SZ_;  // h (v2[1] slot, dead by then)
  float* mid  = ws + 1 * SZ_;  // [T, 4096] over slots 1..4 (all dead by FFN)
  float* counts = ws + 7 * SZ_;
  float* psum = counts + E_;
  int* ecnt = (int*)(psum + E_);
  int* etok = ecnt + E_;
  float* ewt = (float*)(etok + E_ * T_);

  hipMemsetAsync(counts, 0, (E_ * 3) * sizeof(float), stream);

  // 1. LN1
  ln_kernel<<<T_, 256, 0, stream>>>(x, g1, be1, xn);
  // 2. Router
  router_kernel<<<T_, 256, 0, stream>>>(xn, Wr, counts, psum, ecnt, etok, ewt);
  // 3. Grouped per-expert projections q, k, v  (two-slot outputs, no atomics)
  dim3 gmoe(D_ / 64, T_ / 64, E_);
  moe_gemm<<<gmoe, 256, 0, stream>>>(xn, Wq, q2, SZ_, ecnt, etok, ewt);
  moe_gemm<<<gmoe, 256, 0, stream>>>(xn, Wk, k2, SZ_, ecnt, etok, ewt);
  moe_gemm<<<gmoe, 256, 0, stream>>>(xn, Wv, v2, SZ_, ecnt, etok, ewt);
  // 4. Combine slot pairs in-place (q = q0 + q1, etc.)
  add2_kernel<<<SZ_ / 4 / 256, 256, 0, stream>>>(q2, q2 + SZ_);
  add2_kernel<<<SZ_ / 4 / 256, 256, 0, stream>>>(k2, k2 + SZ_);
  add2_kernel<<<SZ_ / 4 / 256, 256, 0, stream>>>(v2, v2 + SZ_);
  // 5. Attention (writes attn_out into xn slot)
  attn_kernel<<<dim3(B_ * H_, N_ / 64), 256, 0, stream>>>(q2, k2, v2, xn);
  // 6. Output projection (gathered, two-slot)
  moe_gemm<<<gmoe, 256, 0, stream>>>(xn, Wo, o2a, 2 * SZ_, ecnt, etok, ewt);
  // 7. h = x + o0 + o1 ; hn2 = LN(h)  (hn2 into slot 0)
  hln2_kernel<<<T_, 256, 0, stream>>>(x, o2a, o2b, g2, be2, hbuf, xn);
  // 8. FFN
  ffn1_kernel<<<dim3(FF_ / 64, T_ / 64), 256, 0, stream>>>(xn, W1, b1, mid);
  ffn2_kernel<<<dim3(D_ / 64, T_ / 64), 256, 0, stream>>>(mid, W2, b2, hbuf, y);
  // 9. load-balance scalar
  lb_kernel<<<1, 64, 0, stream>>>(counts, psum, y + SZ_);
}

// Round 2
// 2459.656 us; speedup vs baseline: 1.2175x; 1.2175x over previous
//
#include <hip/hip_runtime.h>

#define B_ 4
#define N_ 1024
#define D_ 1024
#define H_ 16
#define HD_ 64
#define E_ 12
#define T_ 4096
#define FF_ 4096

static constexpr size_t SZ_ = (size_t)T_ * D_;

__device__ __forceinline__ float wave_sum64(float v) {
#pragma unroll
  for (int o = 32; o > 0; o >>= 1) v += __shfl_down(v, o);
  return v;
}

__device__ __forceinline__ float gelu_f(float x) {
  // jax.nn.gelu approximate=True (tanh form)
  float u = 0.7978845608028654f * (x + 0.044715f * x * x * x);
  u = fminf(fmaxf(u, -15.f), 15.f);
  float e = __expf(2.f * u);
  float th = (e - 1.f) / (e + 1.f);
  return 0.5f * x * (1.f + th);
}

// ---------------- LayerNorm (one block per token, 256 thr, D=1024) ----------
__global__ __launch_bounds__(256) void ln_kernel(const float* __restrict__ x,
    const float* __restrict__ g, const float* __restrict__ b,
    float* __restrict__ out) {
  const int t = blockIdx.x, tid = threadIdx.x;
  const size_t base = (size_t)t * D_;
  const float4 v = ((const float4*)(x + base))[tid];
  float s = v.x + v.y + v.z + v.w;
  float s2 = v.x * v.x + v.y * v.y + v.z * v.z + v.w * v.w;
  s = wave_sum64(s);
  s2 = wave_sum64(s2);
  __shared__ float ls[4], ls2[4];
  const int w = tid >> 6;
  if ((tid & 63) == 0) { ls[w] = s; ls2[w] = s2; }
  __syncthreads();
  const float mean = (ls[0] + ls[1] + ls[2] + ls[3]) * (1.0f / D_);
  const float var = (ls2[0] + ls2[1] + ls2[2] + ls2[3]) * (1.0f / D_) - mean * mean;
  const float inv = rsqrtf(var + 1e-5f);
  const float4 gg = ((const float4*)g)[tid];
  const float4 bb = ((const float4*)b)[tid];
  float4 o4;
  o4.x = (v.x - mean) * inv * gg.x + bb.x;
  o4.y = (v.y - mean) * inv * gg.y + bb.y;
  o4.z = (v.z - mean) * inv * gg.z + bb.z;
  o4.w = (v.w - mean) * inv * gg.w + bb.w;
  ((float4*)(out + base))[tid] = o4;
}

// -------- h = x + o0 + o1; hn = LN(h)  (fused residual + LN2) ---------------
__global__ __launch_bounds__(256) void hln2_kernel(const float* __restrict__ x,
    const float* __restrict__ oa, const float* __restrict__ ob,
    const float* __restrict__ g, const float* __restrict__ be,
    float* __restrict__ hout, float* __restrict__ hn) {
  const int t = blockIdx.x, tid = threadIdx.x;
  const size_t base = (size_t)t * D_;
  const float4 xv = ((const float4*)(x + base))[tid];
  const float4 av = ((const float4*)(oa + base))[tid];
  const float4 bv = ((const float4*)(ob + base))[tid];
  float4 hv;
  hv.x = xv.x + av.x + bv.x;
  hv.y = xv.y + av.y + bv.y;
  hv.z = xv.z + av.z + bv.z;
  hv.w = xv.w + av.w + bv.w;
  ((float4*)(hout + base))[tid] = hv;
  float s = hv.x + hv.y + hv.z + hv.w;
  float s2 = hv.x * hv.x + hv.y * hv.y + hv.z * hv.z + hv.w * hv.w;
  s = wave_sum64(s);
  s2 = wave_sum64(s2);
  __shared__ float ls[4], ls2[4];
  const int w = tid >> 6;
  if ((tid & 63) == 0) { ls[w] = s; ls2[w] = s2; }
  __syncthreads();
  const float mean = (ls[0] + ls[1] + ls[2] + ls[3]) * (1.0f / D_);
  const float var = (ls2[0] + ls2[1] + ls2[2] + ls2[3]) * (1.0f / D_) - mean * mean;
  const float inv = rsqrtf(var + 1e-5f);
  const float4 gg = ((const float4*)g)[tid];
  const float4 bb = ((const float4*)be)[tid];
  float4 o4;
  o4.x = (hv.x - mean) * inv * gg.x + bb.x;
  o4.y = (hv.y - mean) * inv * gg.y + bb.y;
  o4.z = (hv.z - mean) * inv * gg.z + bb.z;
  o4.w = (hv.w - mean) * inv * gg.w + bb.w;
  ((float4*)(hn + base))[tid] = o4;
}

// ------- Router stage 1: logits, softmax, top-2 per token. NO atomics. ------
__global__ __launch_bounds__(256) void router_logits(const float* __restrict__ xn,
    const float* __restrict__ Wr, float* __restrict__ probs,
    int* __restrict__ topi, float2* __restrict__ topw) {
  const int t = blockIdx.x, tid = threadIdx.x;
  const float4 xv = ((const float4*)(xn + (size_t)t * D_))[tid];
  float acc[E_];
#pragma unroll
  for (int e = 0; e < E_; ++e) {
    const float4 wv = ((const float4*)(Wr + (size_t)e * D_))[tid];
    acc[e] = xv.x * wv.x + xv.y * wv.y + xv.z * wv.z + xv.w * wv.w;
  }
#pragma unroll
  for (int e = 0; e < E_; ++e) acc[e] = wave_sum64(acc[e]);
  __shared__ float red[4][E_];
  const int w = tid >> 6;
  if ((tid & 63) == 0) {
#pragma unroll
    for (int e = 0; e < E_; ++e) red[w][e] = acc[e];
  }
  __syncthreads();
  if (tid == 0) {
    float lg[E_];
    float mx = -1e30f;
#pragma unroll
    for (int e = 0; e < E_; ++e) {
      lg[e] = red[0][e] + red[1][e] + red[2][e] + red[3][e];
      mx = fmaxf(mx, lg[e]);
    }
    float p[E_];
    float sum = 0.f;
#pragma unroll
    for (int e = 0; e < E_; ++e) { p[e] = __expf(lg[e] - mx); sum += p[e]; }
    const float invs = 1.f / sum;
#pragma unroll
    for (int e = 0; e < E_; ++e) {
      p[e] *= invs;
      probs[t * E_ + e] = p[e];
    }
    int i0 = 0;
#pragma unroll
    for (int e = 1; e < E_; ++e) if (p[e] > p[i0]) i0 = e;
    int i1 = (i0 == 0) ? 1 : 0;
#pragma unroll
    for (int e = 0; e < E_; ++e) if (e != i0 && p[e] > p[i1]) i1 = e;
    const float rs = 1.f / (p[i0] + p[i1] + 1e-6f);
    topi[t] = i0 | (i1 << 8);
    topw[t] = make_float2(p[i0] * rs, p[i1] * rs);
  }
}

// ------- Router stage 2: psum[e] = sum_t probs[t][e] (one block) ------------
__global__ __launch_bounds__(256) void psum_kernel(const float* __restrict__ probs,
                                                   float* __restrict__ psum) {
  const int tid = threadIdx.x;
  float local[E_] = {};
  for (int t = tid; t < T_; t += 256) {
#pragma unroll
    for (int e = 0; e < E_; ++e) local[e] += probs[t * E_ + e];
  }
#pragma unroll
  for (int e = 0; e < E_; ++e) local[e] = wave_sum64(local[e]);
  __shared__ float red[4][E_];
  const int w = tid >> 6;
  if ((tid & 63) == 0) {
#pragma unroll
    for (int e = 0; e < E_; ++e) red[w][e] = local[e];
  }
  __syncthreads();
  if (tid < E_)
    psum[tid] = red[0][tid] + red[1][tid] + red[2][tid] + red[3][tid];
}

// ------- Router stage 3: per-expert compaction (12 blocks, deterministic) ---
__global__ __launch_bounds__(256) void build_lists(const int* __restrict__ topi,
    const float2* __restrict__ topw, int* __restrict__ ecnt,
    int* __restrict__ etok, float* __restrict__ ewt) {
  const int e = blockIdx.x;
  const int tid = threadIdx.x;
  const int wid = tid >> 6, lane = tid & 63;
  __shared__ int wbase[4];
  __shared__ int base;
  if (tid == 0) base = 0;
  __syncthreads();
  for (int c = 0; c < T_; c += 256) {
    const int t = c + tid;
    const int pk = topi[t];
    const int i0 = pk & 0xFF, i1 = (pk >> 8) & 0xFF;
    const float2 w2 = topw[t];
    const int sel = (i0 == e) ? 0 : ((i1 == e) ? 1 : -1);
    const unsigned long long mask = __ballot(sel >= 0);
    const int prefix = __popcll(mask & ((1ULL << lane) - 1ULL));
    if (lane == 0) wbase[wid] = __popcll(mask);
    __syncthreads();
    if (tid == 0) {
      int s = base;
#pragma unroll
      for (int ww = 0; ww < 4; ++ww) { int cc = wbase[ww]; wbase[ww] = s; s += cc; }
      base = s;
    }
    __syncthreads();
    if (sel >= 0) {
      const int pos = wbase[wid] + prefix;
      etok[e * T_ + pos] = t | (sel << 16);
      ewt[e * T_ + pos] = sel ? w2.y : w2.x;
    }
    __syncthreads();
  }
  if (tid == 0) ecnt[e] = base;
}

// ------- Gathered per-expert GEMM: out[kk*kkStride + tok*D + n] = w*(xn@We.T)
__global__ __launch_bounds__(256) void moe_gemm(const float* __restrict__ in,
    const float* __restrict__ Wall, float* __restrict__ out, size_t kkStride,
    const int* __restrict__ ecnt, const int* __restrict__ etok,
    const float* __restrict__ ewt) {
  const int e = blockIdx.z;
  const int Me = ecnt[e];
  const int m0 = blockIdx.y * 64;
  if (m0 >= Me) return;
  const int n0 = blockIdx.x * 64;
  const float* W = Wall + (size_t)e * D_ * D_;
  __shared__ __align__(16) float As[16][68];
  __shared__ __align__(16) float Bs[16][68];
  __shared__ int stok[64];
  __shared__ float swt[64];
  const int tid = threadIdx.x;
  if (tid < 64) {
    const int s = m0 + tid;
    if (s < Me) { stok[tid] = etok[e * T_ + s]; swt[tid] = ewt[e * T_ + s]; }
    else        { stok[tid] = 0;                swt[tid] = 0.f; }
  }
  __syncthreads();
  const int lm = tid >> 2;
  const int lk = (tid & 3) * 4;
  const int tx = tid & 15, ty = tid >> 4;
  const float* arow = in + (size_t)(stok[lm] & 0xFFFF) * D_ + lk;
  const float* brow = W + (size_t)(n0 + lm) * D_ + lk;
  float acc[4][4] = {};
  for (int kt = 0; kt < D_; kt += 16) {
    const float4 a4 = *(const float4*)(arow + kt);
    const float4 b4 = *(const float4*)(brow + kt);
    As[lk + 0][lm] = a4.x; As[lk + 1][lm] = a4.y;
    As[lk + 2][lm] = a4.z; As[lk + 3][lm] = a4.w;
    Bs[lk + 0][lm] = b4.x; Bs[lk + 1][lm] = b4.y;
    Bs[lk + 2][lm] = b4.z; Bs[lk + 3][lm] = b4.w;
    __syncthreads();
#pragma unroll
    for (int kk = 0; kk < 16; ++kk) {
      const float4 av = *(const float4*)&As[kk][ty * 4];
      const float4 bv = *(const float4*)&Bs[kk][tx * 4];
      const float a_[4] = {av.x, av.y, av.z, av.w};
      const float b_[4] = {bv.x, bv.y, bv.z, bv.w};
#pragma unroll
      for (int i = 0; i < 4; ++i)
#pragma unroll
        for (int j = 0; j < 4; ++j) acc[i][j] = fmaf(a_[i], b_[j], acc[i][j]);
    }
    __syncthreads();
  }
#pragma unroll
  for (int i = 0; i < 4; ++i) {
    const int srow = ty * 4 + i;
    if (m0 + srow < Me) {
      const int pk = stok[srow];
      const int tok = pk & 0xFFFF;
      const size_t kk = (size_t)(pk >> 16);
      const float wv = swt[srow];
      float4 r;
      r.x = acc[i][0] * wv; r.y = acc[i][1] * wv;
      r.z = acc[i][2] * wv; r.w = acc[i][3] * wv;
      *(float4*)(out + kk * kkStride + (size_t)tok * D_ + n0 + tx * 4) = r;
    }
  }
}

// ---------------- in-place a += b (float4) ----------------------------------
__global__ __launch_bounds__(256) void add2_kernel(float* __restrict__ a,
                                                   const float* __restrict__ b) {
  const size_t i = (size_t)blockIdx.x * 256 + threadIdx.x;
  float4 x = ((float4*)a)[i];
  const float4 yv = ((const float4*)b)[i];
  x.x += yv.x; x.y += yv.y; x.z += yv.z; x.w += yv.w;
  ((float4*)a)[i] = x;
}

// ---------------- Flash attention, 64-row q tile per block ------------------
__global__ __launch_bounds__(256) void attn_kernel(const float* __restrict__ q,
    const float* __restrict__ k, const float* __restrict__ v,
    float* __restrict__ out) {
  const int bh = blockIdx.x;
  const int b = bh >> 4, h = bh & 15;
  const int q0 = blockIdx.y * 64;
  const int tid = threadIdx.x;
  const int tx = tid & 15, ty = tid >> 4;
  __shared__ __align__(16) float Qs[64][64];  // [d][r]
  __shared__ __align__(16) float Ks[64][64];  // [d][c]
  __shared__ __align__(16) float Vs[64][64];  // [kv][c]
  __shared__ __align__(16) float Ps[64][64];  // [r][c]
  {
    const int r = tid >> 2, d0 = (tid & 3) * 16;
    const float* src = q + ((size_t)(b * N_ + q0 + r)) * D_ + h * HD_ + d0;
#pragma unroll
    for (int j = 0; j < 16; j += 4) {
      const float4 t4 = *(const float4*)(src + j);
      Qs[d0 + j + 0][r] = t4.x * 0.125f;
      Qs[d0 + j + 1][r] = t4.y * 0.125f;
      Qs[d0 + j + 2][r] = t4.z * 0.125f;
      Qs[d0 + j + 3][r] = t4.w * 0.125f;
    }
  }
  float m_i[4], l_i[4], o_acc[4][4];
#pragma unroll
  for (int i = 0; i < 4; ++i) {
    m_i[i] = -3.0e38f;
    l_i[i] = 0.f;
#pragma unroll
    for (int j = 0; j < 4; ++j) o_acc[i][j] = 0.f;
  }
  for (int kt = 0; kt < 16; ++kt) {
    __syncthreads();  // Q ready (kt=0) / prev PV done before K,V overwrite
    {
      const int r = tid >> 2, d0 = (tid & 3) * 16;
      const float* ks = k + ((size_t)(b * N_ + kt * 64 + r)) * D_ + h * HD_ + d0;
      const float* vs = v + ((size_t)(b * N_ + kt * 64 + r)) * D_ + h * HD_ + d0;
#pragma unroll
      for (int j = 0; j < 16; j += 4) {
        const float4 t4 = *(const float4*)(ks + j);
        Ks[d0 + j + 0][r] = t4.x; Ks[d0 + j + 1][r] = t4.y;
        Ks[d0 + j + 2][r] = t4.z; Ks[d0 + j + 3][r] = t4.w;
        const float4 u4 = *(const float4*)(vs + j);
        *(float4*)&Vs[r][d0 + j] = u4;
      }
    }
    __syncthreads();
    float s[4][4] = {};
#pragma unroll 8
    for (int d = 0; d < 64; ++d) {
      const float4 av = *(const float4*)&Qs[d][ty * 4];
      const float4 bv = *(const float4*)&Ks[d][tx * 4];
      const float a_[4] = {av.x, av.y, av.z, av.w};
      const float b_[4] = {bv.x, bv.y, bv.z, bv.w};
#pragma unroll
      for (int i = 0; i < 4; ++i)
#pragma unroll
        for (int j = 0; j < 4; ++j) s[i][j] = fmaf(a_[i], b_[j], s[i][j]);
    }
    float alpha[4];
#pragma unroll
    for (int i = 0; i < 4; ++i) {
      float mt = fmaxf(fmaxf(s[i][0], s[i][1]), fmaxf(s[i][2], s[i][3]));
#pragma unroll
      for (int o = 8; o > 0; o >>= 1) mt = fmaxf(mt, __shfl_xor(mt, o));
      const float mn = fmaxf(m_i[i], mt);
      alpha[i] = __expf(m_i[i] - mn);
      m_i[i] = mn;
      float rsum = 0.f;
#pragma unroll
      for (int j = 0; j < 4; ++j) { s[i][j] = __expf(s[i][j] - mn); rsum += s[i][j]; }
#pragma unroll
      for (int o = 8; o > 0; o >>= 1) rsum += __shfl_xor(rsum, o);
      l_i[i] = l_i[i] * alpha[i] + rsum;
      Ps[ty * 4 + i][tx * 4 + 0] = s[i][0];
      Ps[ty * 4 + i][tx * 4 + 1] = s[i][1];
      Ps[ty * 4 + i][tx * 4 + 2] = s[i][2];
      Ps[ty * 4 + i][tx * 4 + 3] = s[i][3];
    }
    __syncthreads();
#pragma unroll
    for (int i = 0; i < 4; ++i)
#pragma unroll
      for (int j = 0; j < 4; ++j) o_acc[i][j] *= alpha[i];
#pragma unroll 8
    for (int d = 0; d < 64; ++d) {
      const float4 vv = *(const float4*)&Vs[d][tx * 4];
      const float v_[4] = {vv.x, vv.y, vv.z, vv.w};
      const float p0 = Ps[ty * 4 + 0][d];
      const float p1 = Ps[ty * 4 + 1][d];
      const float p2 = Ps[ty * 4 + 2][d];
      const float p3 = Ps[ty * 4 + 3][d];
#pragma unroll
      for (int j = 0; j < 4; ++j) {
        o_acc[0][j] = fmaf(p0, v_[j], o_acc[0][j]);
        o_acc[1][j] = fmaf(p1, v_[j], o_acc[1][j]);
        o_acc[2][j] = fmaf(p2, v_[j], o_acc[2][j]);
        o_acc[3][j] = fmaf(p3, v_[j], o_acc[3][j]);
      }
    }
  }
#pragma unroll
  for (int i = 0; i < 4; ++i) {
    const float inv = 1.f / l_i[i];
    float4 o4;
    o4.x = o_acc[i][0] * inv; o4.y = o_acc[i][1] * inv;
    o4.z = o_acc[i][2] * inv; o4.w = o_acc[i][3] * inv;
    *(float4*)(out + ((size_t)(b * N_ + q0 + ty * 4 + i)) * D_ + h * HD_ + tx * 4) = o4;
  }
}

// ---------------- FFN GEMM 1: mid = gelu(hn2 @ W1.T + b1) -------------------
__global__ __launch_bounds__(256) void ffn1_kernel(const float* __restrict__ A,
    const float* __restrict__ W, const float* __restrict__ bias,
    float* __restrict__ mid) {
  const int m0 = blockIdx.y * 64, n0 = blockIdx.x * 64;
  __shared__ __align__(16) float As[16][68];
  __shared__ __align__(16) float Bs[16][68];
  const int tid = threadIdx.x;
  const int lm = tid >> 2, lk = (tid & 3) * 4;
  const int tx = tid & 15, ty = tid >> 4;
  const float* arow = A + (size_t)(m0 + lm) * D_ + lk;
  const float* brow = W + (size_t)(n0 + lm) * D_ + lk;
  float acc[4][4] = {};
  for (int kt = 0; kt < D_; kt += 16) {
    const float4 a4 = *(const float4*)(arow + kt);
    const float4 b4 = *(const float4*)(brow + kt);
    As[lk + 0][lm] = a4.x; As[lk + 1][lm] = a4.y;
    As[lk + 2][lm] = a4.z; As[lk + 3][lm] = a4.w;
    Bs[lk + 0][lm] = b4.x; Bs[lk + 1][lm] = b4.y;
    Bs[lk + 2][lm] = b4.z; Bs[lk + 3][lm] = b4.w;
    __syncthreads();
#pragma unroll
    for (int kk = 0; kk < 16; ++kk) {
      const float4 av = *(const float4*)&As[kk][ty * 4];
      const float4 bv = *(const float4*)&Bs[kk][tx * 4];
      const float a_[4] = {av.x, av.y, av.z, av.w};
      const float b_[4] = {bv.x, bv.y, bv.z, bv.w};
#pragma unroll
      for (int i = 0; i < 4; ++i)
#pragma unroll
        for (int j = 0; j < 4; ++j) acc[i][j] = fmaf(a_[i], b_[j], acc[i][j]);
    }
    __syncthreads();
  }
  const float4 bv4 = *(const float4*)(bias + n0 + tx * 4);
  const float bb[4] = {bv4.x, bv4.y, bv4.z, bv4.w};
#pragma unroll
  for (int i = 0; i < 4; ++i) {
    float4 r;
    r.x = gelu_f(acc[i][0] + bb[0]);
    r.y = gelu_f(acc[i][1] + bb[1]);
    r.z = gelu_f(acc[i][2] + bb[2]);
    r.w = gelu_f(acc[i][3] + bb[3]);
    *(float4*)(mid + (size_t)(m0 + ty * 4 + i) * FF_ + n0 + tx * 4) = r;
  }
}

// ------------- FFN GEMM 2: y = h + mid @ W2.T + b2 --------------------------
__global__ __launch_bounds__(256) void ffn2_kernel(const float* __restrict__ A,
    const float* __restrict__ W, const float* __restrict__ bias,
    const float* __restrict__ hres, float* __restrict__ y) {
  const int m0 = blockIdx.y * 64, n0 = blockIdx.x * 64;
  __shared__ __align__(16) float As[16][68];
  __shared__ __align__(16) float Bs[16][68];
  const int tid = threadIdx.x;
  const int lm = tid >> 2, lk = (tid & 3) * 4;
  const int tx = tid & 15, ty = tid >> 4;
  const float* arow = A + (size_t)(m0 + lm) * FF_ + lk;
  const float* brow = W + (size_t)(n0 + lm) * FF_ + lk;
  float acc[4][4] = {};
  for (int kt = 0; kt < FF_; kt += 16) {
    const float4 a4 = *(const float4*)(arow + kt);
    const float4 b4 = *(const float4*)(brow + kt);
    As[lk + 0][lm] = a4.x; As[lk + 1][lm] = a4.y;
    As[lk + 2][lm] = a4.z; As[lk + 3][lm] = a4.w;
    Bs[lk + 0][lm] = b4.x; Bs[lk + 1][lm] = b4.y;
    Bs[lk + 2][lm] = b4.z; Bs[lk + 3][lm] = b4.w;
    __syncthreads();
#pragma unroll
    for (int kk = 0; kk < 16; ++kk) {
      const float4 av = *(const float4*)&As[kk][ty * 4];
      const float4 bv = *(const float4*)&Bs[kk][tx * 4];
      const float a_[4] = {av.x, av.y, av.z, av.w};
      const float b_[4] = {bv.x, bv.y, bv.z, bv.w};
#pragma unroll
      for (int i = 0; i < 4; ++i)
#pragma unroll
        for (int j = 0; j < 4; ++j) acc[i][j] = fmaf(a_[i], b_[j], acc[i][j]);
    }
    __syncthreads();
  }
  const float4 bv4 = *(const float4*)(bias + n0 + tx * 4);
  const float bb[4] = {bv4.x, bv4.y, bv4.z, bv4.w};
#pragma unroll
  for (int i = 0; i < 4; ++i) {
    const int row = m0 + ty * 4 + i;
    const float4 hv = *(const float4*)(hres + (size_t)row * D_ + n0 + tx * 4);
    float4 r;
    r.x = acc[i][0] + bb[0] + hv.x;
    r.y = acc[i][1] + bb[1] + hv.y;
    r.z = acc[i][2] + bb[2] + hv.z;
    r.w = acc[i][3] + bb[3] + hv.w;
    *(float4*)(y + (size_t)row * D_ + n0 + tx * 4) = r;
  }
}

// ---------------- load-balance scalar ---------------------------------------
__global__ void lb_kernel(const int* __restrict__ ecnt,
                          const float* __restrict__ psum, float* __restrict__ out) {
  if (threadIdx.x == 0 && blockIdx.x == 0) {
    float tot = 0.f;
    for (int e = 0; e < E_; ++e) tot += (float)ecnt[e];
    float s = 0.f;
    for (int e = 0; e < E_; ++e) s += (float)ecnt[e] / (tot + 1e-6f) * psum[e];
    out[0] = s * (float)E_;
  }
}

extern "C" void kernel_launch(void* const* d_in, const int* in_sizes, int n_in,
                              void* d_out, int out_size, void* d_ws, size_t ws_size,
                              hipStream_t stream) {
  (void)in_sizes; (void)n_in; (void)out_size; (void)ws_size;
  const float* x  = (const float*)d_in[0];
  const float* Wr = (const float*)d_in[1];
  const float* Wq = (const float*)d_in[2];
  const float* Wk = (const float*)d_in[3];
  const float* Wv = (const float*)d_in[4];
  const float* Wo = (const float*)d_in[5];
  const float* W1 = (const float*)d_in[6];
  const float* b1 = (const float*)d_in[7];
  const float* W2 = (const float*)d_in[8];
  const float* b2 = (const float*)d_in[9];
  const float* g1 = (const float*)d_in[10];
  const float* be1 = (const float*)d_in[11];
  const float* g2 = (const float*)d_in[12];
  const float* be2 = (const float*)d_in[13];
  float* y = (float*)d_out;
  float* ws = (float*)d_ws;

  // workspace slots (each SZ_ = T*D floats = 16 MB)
  float* xn   = ws + 0 * SZ_;  // later: attn_out, then hn2
  float* q2   = ws + 1 * SZ_;  // [2][T][D]; combined q in first half; later mid
  float* k2   = ws + 3 * SZ_;  // [2][T][D]
  float* v2   = ws + 5 * SZ_;  // [2][T][D]
  float* o2a  = ws + 2 * SZ_;  // o slot 0 (q2[1] slot, dead by then)
  float* o2b  = ws + 4 * SZ_;  // o slot 1 (k2[1] slot, dead by then)
  float* hbuf = ws + 6 * SZ_;  // h (v2[1] slot, dead by then)
  float* mid  = ws + 1 * SZ_;  // [T, 4096] over slots 1..4 (all dead by FFN)
  float* tail = ws + 7 * SZ_;
  float* psum  = tail;                       // [E]
  int*   ecnt  = (int*)(psum + E_);          // [E]
  int*   etok  = ecnt + E_;                  // [E*T]
  float* ewt   = (float*)(etok + E_ * T_);   // [E*T]
  float* probs = ewt + E_ * T_;              // [T*E]
  int*   topi  = (int*)(probs + T_ * E_);    // [T]
  float2* topw = (float2*)(topi + T_);       // [T]

  // 1. LN1
  ln_kernel<<<T_, 256, 0, stream>>>(x, g1, be1, xn);
  // 2. Router (3 stages, deterministic, no contended atomics)
  router_logits<<<T_, 256, 0, stream>>>(xn, Wr, probs, topi, topw);
  psum_kernel<<<1, 256, 0, stream>>>(probs, psum);
  build_lists<<<E_, 256, 0, stream>>>(topi, topw, ecnt, etok, ewt);
  // 3. Grouped per-expert projections q, k, v  (two-slot outputs, no atomics)
  dim3 gmoe(D_ / 64, T_ / 64, E_);
  moe_gemm<<<gmoe, 256, 0, stream>>>(xn, Wq, q2, SZ_, ecnt, etok, ewt);
  moe_gemm<<<gmoe, 256, 0, stream>>>(xn, Wk, k2, SZ_, ecnt, etok, ewt);
  moe_gemm<<<gmoe, 256, 0, stream>>>(xn, Wv, v2, SZ_, ecnt, etok, ewt);
  // 4. Combine slot pairs in-place (q = q0 + q1, etc.)
  add2_kernel<<<SZ_ / 4 / 256, 256, 0, stream>>>(q2, q2 + SZ_);
  add2_kernel<<<SZ_ / 4 / 256, 256, 0, stream>>>(k2, k2 + SZ_);
  add2_kernel<<<SZ_ / 4 / 256, 256, 0, stream>>>(v2, v2 + SZ_);
  // 5. Attention (writes attn_out into xn slot)
  attn_kernel<<<dim3(B_ * H_, N_ / 64), 256, 0, stream>>>(q2, k2, v2, xn);
  // 6. Output projection (gathered, two-slot)
  moe_gemm<<<gmoe, 256, 0, stream>>>(xn, Wo, o2a, 2 * SZ_, ecnt, etok, ewt);
  // 7. h = x + o0 + o1 ; hn2 = LN(h)  (hn2 into slot 0)
  hln2_kernel<<<T_, 256, 0, stream>>>(x, o2a, o2b, g2, be2, hbuf, xn);
  // 8. FFN
  ffn1_kernel<<<dim3(FF_ / 64, T_ / 64), 256, 0, stream>>>(xn, W1, b1, mid);
  ffn2_kernel<<<dim3(D_ / 64, T_ / 64), 256, 0, stream>>>(mid, W2, b2, hbuf, y);
  // 9. load-balance scalar
  lb_kernel<<<1, 64, 0, stream>>>(ecnt, psum, y + SZ_);
}

// Round 3
// 941.303 us; speedup vs baseline: 3.1815x; 2.6130x over previous
//
#include <hip/hip_runtime.h>

#define B_ 4
#define N_ 1024
#define D_ 1024
#define H_ 16
#define HD_ 64
#define E_ 12
#define T_ 4096
#define FF_ 4096

static constexpr size_t SZ_ = (size_t)T_ * D_;

typedef __attribute__((ext_vector_type(8))) short bhalf8;
typedef __attribute__((ext_vector_type(4))) float f32x4;

#define GLDS(gp, lp)                                                         \
  __builtin_amdgcn_global_load_lds(                                          \
      (const __attribute__((address_space(1))) void*)(gp),                   \
      (__attribute__((address_space(3))) void*)(lp), 16, 0, 0)

__device__ __forceinline__ float wave_sum64(float v) {
#pragma unroll
  for (int o = 32; o > 0; o >>= 1) v += __shfl_down(v, o);
  return v;
}

__device__ __forceinline__ unsigned short f2bf(float f) {
  unsigned u = __float_as_uint(f);
  u += 0x7FFFu + ((u >> 16) & 1u);
  return (unsigned short)(u >> 16);
}
__device__ __forceinline__ float b2f(unsigned short s) {
  return __uint_as_float(((unsigned)s) << 16);
}
__device__ __forceinline__ unsigned addpair_bf(unsigned x, unsigned y) {
  float lo = b2f((unsigned short)(x & 0xffff)) + b2f((unsigned short)(y & 0xffff));
  float hi = b2f((unsigned short)(x >> 16)) + b2f((unsigned short)(y >> 16));
  return (unsigned)f2bf(lo) | ((unsigned)f2bf(hi) << 16);
}

__device__ __forceinline__ float gelu_f(float x) {
  float u = 0.7978845608028654f * (x + 0.044715f * x * x * x);
  u = fminf(fmaxf(u, -15.f), 15.f);
  float e = __expf(2.f * u);
  float th = (e - 1.f) / (e + 1.f);
  return 0.5f * x * (1.f + th);
}

// swizzled LDS slot for (row, kseg): keeps glds lane-contiguity AND 2-way-max
// bank aliasing on ds_read_b128 frag reads
__device__ __forceinline__ int slot_of(int row, int q) {
  return row * 4 + (q ^ ((row >> 1) & 3));
}

// ---------------- LayerNorm: fp32 out + bf16 out ----------------------------
__global__ __launch_bounds__(256) void ln_kernel(const float* __restrict__ x,
    const float* __restrict__ g, const float* __restrict__ b,
    float* __restrict__ out, unsigned short* __restrict__ outb) {
  const int t = blockIdx.x, tid = threadIdx.x;
  const size_t base = (size_t)t * D_;
  const float4 v = ((const float4*)(x + base))[tid];
  float s = v.x + v.y + v.z + v.w;
  float s2 = v.x * v.x + v.y * v.y + v.z * v.z + v.w * v.w;
  s = wave_sum64(s);
  s2 = wave_sum64(s2);
  __shared__ float ls[4], ls2[4];
  const int w = tid >> 6;
  if ((tid & 63) == 0) { ls[w] = s; ls2[w] = s2; }
  __syncthreads();
  const float mean = (ls[0] + ls[1] + ls[2] + ls[3]) * (1.0f / D_);
  const float var = (ls2[0] + ls2[1] + ls2[2] + ls2[3]) * (1.0f / D_) - mean * mean;
  const float inv = rsqrtf(var + 1e-5f);
  const float4 gg = ((const float4*)g)[tid];
  const float4 bb = ((const float4*)b)[tid];
  float4 o4;
  o4.x = (v.x - mean) * inv * gg.x + bb.x;
  o4.y = (v.y - mean) * inv * gg.y + bb.y;
  o4.z = (v.z - mean) * inv * gg.z + bb.z;
  o4.w = (v.w - mean) * inv * gg.w + bb.w;
  ((float4*)(out + base))[tid] = o4;
  ushort4 u4;
  u4.x = f2bf(o4.x); u4.y = f2bf(o4.y); u4.z = f2bf(o4.z); u4.w = f2bf(o4.w);
  ((ushort4*)(outb + base))[tid] = u4;
}

// ---- h = x + o0 + o1 (bf16 slots); hn = LN(h): h fp32 + hn bf16 ------------
__global__ __launch_bounds__(256) void hln2_kernel(const float* __restrict__ x,
    const unsigned short* __restrict__ oa, const unsigned short* __restrict__ ob,
    const float* __restrict__ g, const float* __restrict__ be,
    float* __restrict__ hout, unsigned short* __restrict__ hnb) {
  const int t = blockIdx.x, tid = threadIdx.x;
  const size_t base = (size_t)t * D_;
  const float4 xv = ((const float4*)(x + base))[tid];
  const ushort4 av = ((const ushort4*)(oa + base))[tid];
  const ushort4 bv = ((const ushort4*)(ob + base))[tid];
  float4 hv;
  hv.x = xv.x + b2f(av.x) + b2f(bv.x);
  hv.y = xv.y + b2f(av.y) + b2f(bv.y);
  hv.z = xv.z + b2f(av.z) + b2f(bv.z);
  hv.w = xv.w + b2f(av.w) + b2f(bv.w);
  ((float4*)(hout + base))[tid] = hv;
  float s = hv.x + hv.y + hv.z + hv.w;
  float s2 = hv.x * hv.x + hv.y * hv.y + hv.z * hv.z + hv.w * hv.w;
  s = wave_sum64(s);
  s2 = wave_sum64(s2);
  __shared__ float ls[4], ls2[4];
  const int w = tid >> 6;
  if ((tid & 63) == 0) { ls[w] = s; ls2[w] = s2; }
  __syncthreads();
  const float mean = (ls[0] + ls[1] + ls[2] + ls[3]) * (1.0f / D_);
  const float var = (ls2[0] + ls2[1] + ls2[2] + ls2[3]) * (1.0f / D_) - mean * mean;
  const float inv = rsqrtf(var + 1e-5f);
  const float4 gg = ((const float4*)g)[tid];
  const float4 bb = ((const float4*)be)[tid];
  ushort4 o4;
  o4.x = f2bf((hv.x - mean) * inv * gg.x + bb.x);
  o4.y = f2bf((hv.y - mean) * inv * gg.y + bb.y);
  o4.z = f2bf((hv.z - mean) * inv * gg.z + bb.z);
  o4.w = f2bf((hv.w - mean) * inv * gg.w + bb.w);
  ((ushort4*)(hnb + base))[tid] = o4;
}

// ------- Router stage 1 (fp32 path, deterministic selection) ----------------
__global__ __launch_bounds__(256) void router_logits(const float* __restrict__ xn,
    const float* __restrict__ Wr, float* __restrict__ probs,
    int* __restrict__ topi, float2* __restrict__ topw) {
  const int t = blockIdx.x, tid = threadIdx.x;
  const float4 xv = ((const float4*)(xn + (size_t)t * D_))[tid];
  float acc[E_];
#pragma unroll
  for (int e = 0; e < E_; ++e) {
    const float4 wv = ((const float4*)(Wr + (size_t)e * D_))[tid];
    acc[e] = xv.x * wv.x + xv.y * wv.y + xv.z * wv.z + xv.w * wv.w;
  }
#pragma unroll
  for (int e = 0; e < E_; ++e) acc[e] = wave_sum64(acc[e]);
  __shared__ float red[4][E_];
  const int w = tid >> 6;
  if ((tid & 63) == 0) {
#pragma unroll
    for (int e = 0; e < E_; ++e) red[w][e] = acc[e];
  }
  __syncthreads();
  if (tid == 0) {
    float lg[E_];
    float mx = -1e30f;
#pragma unroll
    for (int e = 0; e < E_; ++e) {
      lg[e] = red[0][e] + red[1][e] + red[2][e] + red[3][e];
      mx = fmaxf(mx, lg[e]);
    }
    float p[E_];
    float sum = 0.f;
#pragma unroll
    for (int e = 0; e < E_; ++e) { p[e] = __expf(lg[e] - mx); sum += p[e]; }
    const float invs = 1.f / sum;
#pragma unroll
    for (int e = 0; e < E_; ++e) {
      p[e] *= invs;
      probs[t * E_ + e] = p[e];
    }
    int i0 = 0;
#pragma unroll
    for (int e = 1; e < E_; ++e) if (p[e] > p[i0]) i0 = e;
    int i1 = (i0 == 0) ? 1 : 0;
#pragma unroll
    for (int e = 0; e < E_; ++e) if (e != i0 && p[e] > p[i1]) i1 = e;
    const float rs = 1.f / (p[i0] + p[i1] + 1e-6f);
    topi[t] = i0 | (i1 << 8);
    topw[t] = make_float2(p[i0] * rs, p[i1] * rs);
  }
}

__global__ __launch_bounds__(256) void psum_kernel(const float* __restrict__ probs,
                                                   float* __restrict__ psum) {
  const int tid = threadIdx.x;
  float local[E_] = {};
  for (int t = tid; t < T_; t += 256) {
#pragma unroll
    for (int e = 0; e < E_; ++e) local[e] += probs[t * E_ + e];
  }
#pragma unroll
  for (int e = 0; e < E_; ++e) local[e] = wave_sum64(local[e]);
  __shared__ float red[4][E_];
  const int w = tid >> 6;
  if ((tid & 63) == 0) {
#pragma unroll
    for (int e = 0; e < E_; ++e) red[w][e] = local[e];
  }
  __syncthreads();
  if (tid < E_)
    psum[tid] = red[0][tid] + red[1][tid] + red[2][tid] + red[3][tid];
}

__global__ __launch_bounds__(256) void build_lists(const int* __restrict__ topi,
    const float2* __restrict__ topw, int* __restrict__ ecnt,
    int* __restrict__ etok, float* __restrict__ ewt) {
  const int e = blockIdx.x;
  const int tid = threadIdx.x;
  const int wid = tid >> 6, lane = tid & 63;
  __shared__ int wbase[4];
  __shared__ int base;
  if (tid == 0) base = 0;
  __syncthreads();
  for (int c = 0; c < T_; c += 256) {
    const int t = c + tid;
    const int pk = topi[t];
    const int i0 = pk & 0xFF, i1 = (pk >> 8) & 0xFF;
    const float2 w2 = topw[t];
    const int sel = (i0 == e) ? 0 : ((i1 == e) ? 1 : -1);
    const unsigned long long mask = __ballot(sel >= 0);
    const int prefix = __popcll(mask & ((1ULL << lane) - 1ULL));
    if (lane == 0) wbase[wid] = __popcll(mask);
    __syncthreads();
    if (tid == 0) {
      int s = base;
#pragma unroll
      for (int ww = 0; ww < 4; ++ww) { int cc = wbase[ww]; wbase[ww] = s; s += cc; }
      base = s;
    }
    __syncthreads();
    if (sel >= 0) {
      const int pos = wbase[wid] + prefix;
      etok[e * T_ + pos] = t | (sel << 16);
      ewt[e * T_ + pos] = sel ? w2.y : w2.x;
    }
    __syncthreads();
  }
  if (tid == 0) ecnt[e] = base;
}

// -------- fp32 -> bf16 weight conversion (float4 per thread) ----------------
__global__ __launch_bounds__(256) void cvtw_kernel(const float* __restrict__ src,
    unsigned short* __restrict__ dst) {
  const size_t i = (size_t)blockIdx.x * 256 + threadIdx.x;
  const float4 v = ((const float4*)src)[i];
  ushort4 o;
  o.x = f2bf(v.x); o.y = f2bf(v.y); o.z = f2bf(v.z); o.w = f2bf(v.w);
  ((ushort4*)dst)[i] = o;
}

// ------- MoE gathered MFMA GEMM: A bf16 (glds gather), B fp32 (on-the-fly cvt)
// out[kk*kkStride + tok*D + n] = bf16( w * (A[tok] @ We.T) )
__global__ __launch_bounds__(256) void moe_mfma(const unsigned short* __restrict__ Ab,
    const float* __restrict__ Wall, unsigned short* __restrict__ out,
    size_t kkStride, const int* __restrict__ ecnt, const int* __restrict__ etok,
    const float* __restrict__ ewt) {
  const int e = blockIdx.z;
  const int Me = ecnt[e];
  const int m0 = blockIdx.y * 128;
  if (m0 >= Me) return;
  const int n0 = blockIdx.x * 128;
  const float* W = Wall + (size_t)e * D_ * D_;
  __shared__ __align__(16) unsigned short As[128 * 32];
  __shared__ __align__(16) unsigned short Bs[128 * 32];
  __shared__ int stok[128];
  __shared__ float swt[128];
  const int tid = threadIdx.x;
  if (tid < 128) {
    const int s = m0 + tid;
    if (s < Me) { stok[tid] = etok[e * T_ + s]; swt[tid] = ewt[e * T_ + s]; }
    else        { stok[tid] = 0;                swt[tid] = 0.f; }
  }
  __syncthreads();
  const int s0 = tid, s1 = tid + 256;
  const int r0 = s0 >> 2, q0 = (s0 & 3) ^ ((r0 >> 1) & 3);
  const int r1 = s1 >> 2, q1 = (s1 & 3) ^ ((r1 >> 1) & 3);
  const unsigned short* aP0 = Ab + (size_t)(stok[r0] & 0xFFFF) * D_ + q0 * 8;
  const unsigned short* aP1 = Ab + (size_t)(stok[r1] & 0xFFFF) * D_ + q1 * 8;
  const float* bP0 = W + (size_t)(n0 + r0) * D_ + q0 * 8;
  const float* bP1 = W + (size_t)(n0 + r1) * D_ + q1 * 8;
  char* AsC = (char*)As;
  char* BsC = (char*)Bs;
  const int wave = tid >> 6, lane = tid & 63;
  const int wm0 = (wave >> 1) * 64, wn0 = (wave & 1) * 64;
  const int lr = lane & 15, lq = lane >> 4;
  int aoff[4], boff[4];
#pragma unroll
  for (int t = 0; t < 4; ++t) {
    aoff[t] = slot_of(wm0 + t * 16 + lr, lq) * 16;
    boff[t] = slot_of(wn0 + t * 16 + lr, lq) * 16;
  }
  f32x4 acc[4][4];
#pragma unroll
  for (int i = 0; i < 4; ++i)
#pragma unroll
    for (int j = 0; j < 4; ++j) acc[i][j] = (f32x4){0.f, 0.f, 0.f, 0.f};
  for (int kt = 0; kt < D_; kt += 32) {
    __syncthreads();
    GLDS(aP0 + kt, AsC + s0 * 16);
    GLDS(aP1 + kt, AsC + s1 * 16);
    const float4 f0 = *(const float4*)(bP0 + kt);
    const float4 f1 = *(const float4*)(bP0 + kt + 4);
    const float4 f2 = *(const float4*)(bP1 + kt);
    const float4 f3 = *(const float4*)(bP1 + kt + 4);
    bhalf8 w0, w1;
    w0[0] = (short)f2bf(f0.x); w0[1] = (short)f2bf(f0.y);
    w0[2] = (short)f2bf(f0.z); w0[3] = (short)f2bf(f0.w);
    w0[4] = (short)f2bf(f1.x); w0[5] = (short)f2bf(f1.y);
    w0[6] = (short)f2bf(f1.z); w0[7] = (short)f2bf(f1.w);
    w1[0] = (short)f2bf(f2.x); w1[1] = (short)f2bf(f2.y);
    w1[2] = (short)f2bf(f2.z); w1[3] = (short)f2bf(f2.w);
    w1[4] = (short)f2bf(f3.x); w1[5] = (short)f2bf(f3.y);
    w1[6] = (short)f2bf(f3.z); w1[7] = (short)f2bf(f3.w);
    *(bhalf8*)(BsC + s0 * 16) = w0;
    *(bhalf8*)(BsC + s1 * 16) = w1;
    __syncthreads();
    bhalf8 af[4], bfr[4];
#pragma unroll
    for (int t = 0; t < 4; ++t) af[t] = *(const bhalf8*)(AsC + aoff[t]);
#pragma unroll
    for (int t = 0; t < 4; ++t) bfr[t] = *(const bhalf8*)(BsC + boff[t]);
#pragma unroll
    for (int i = 0; i < 4; ++i)
#pragma unroll
      for (int j = 0; j < 4; ++j)
        acc[i][j] = __builtin_amdgcn_mfma_f32_16x16x32_bf16(af[i], bfr[j], acc[i][j], 0, 0, 0);
  }
#pragma unroll
  for (int mt = 0; mt < 4; ++mt)
#pragma unroll
    for (int nt = 0; nt < 4; ++nt) {
      const f32x4 c = acc[mt][nt];
      const int col = n0 + wn0 + nt * 16 + lr;
#pragma unroll
      for (int r = 0; r < 4; ++r) {
        const int row = wm0 + mt * 16 + lq * 4 + r;
        if (m0 + row < Me) {
          const int pk = stok[row];
          out[(size_t)(pk >> 16) * kkStride + (size_t)(pk & 0xFFFF) * D_ + col] =
              f2bf(c[r] * swt[row]);
        }
      }
    }
}

// ------- FFN1 MFMA: midb = bf16(gelu(hnb @ W1b.T + b1)) ---------------------
__global__ __launch_bounds__(256) void ffn1_mfma(const unsigned short* __restrict__ Ab,
    const unsigned short* __restrict__ Bb, const float* __restrict__ bias,
    unsigned short* __restrict__ mid) {
  const int m0 = blockIdx.y * 128, n0 = blockIdx.x * 128;
  __shared__ __align__(16) unsigned short As[128 * 32];
  __shared__ __align__(16) unsigned short Bs[128 * 32];
  const int tid = threadIdx.x;
  const int s0 = tid, s1 = tid + 256;
  const int r0 = s0 >> 2, q0 = (s0 & 3) ^ ((r0 >> 1) & 3);
  const int r1 = s1 >> 2, q1 = (s1 & 3) ^ ((r1 >> 1) & 3);
  const unsigned short* aP0 = Ab + (size_t)(m0 + r0) * D_ + q0 * 8;
  const unsigned short* aP1 = Ab + (size_t)(m0 + r1) * D_ + q1 * 8;
  const unsigned short* bP0 = Bb + (size_t)(n0 + r0) * D_ + q0 * 8;
  const unsigned short* bP1 = Bb + (size_t)(n0 + r1) * D_ + q1 * 8;
  char* AsC = (char*)As;
  char* BsC = (char*)Bs;
  const int wave = tid >> 6, lane = tid & 63;
  const int wm0 = (wave >> 1) * 64, wn0 = (wave & 1) * 64;
  const int lr = lane & 15, lq = lane >> 4;
  int aoff[4], boff[4];
#pragma unroll
  for (int t = 0; t < 4; ++t) {
    aoff[t] = slot_of(wm0 + t * 16 + lr, lq) * 16;
    boff[t] = slot_of(wn0 + t * 16 + lr, lq) * 16;
  }
  f32x4 acc[4][4];
#pragma unroll
  for (int i = 0; i < 4; ++i)
#pragma unroll
    for (int j = 0; j < 4; ++j) acc[i][j] = (f32x4){0.f, 0.f, 0.f, 0.f};
  for (int kt = 0; kt < D_; kt += 32) {
    __syncthreads();
    GLDS(aP0 + kt, AsC + s0 * 16);
    GLDS(aP1 + kt, AsC + s1 * 16);
    GLDS(bP0 + kt, BsC + s0 * 16);
    GLDS(bP1 + kt, BsC + s1 * 16);
    __syncthreads();
    bhalf8 af[4], bfr[4];
#pragma unroll
    for (int t = 0; t < 4; ++t) af[t] = *(const bhalf8*)(AsC + aoff[t]);
#pragma unroll
    for (int t = 0; t < 4; ++t) bfr[t] = *(const bhalf8*)(BsC + boff[t]);
#pragma unroll
    for (int i = 0; i < 4; ++i)
#pragma unroll
      for (int j = 0; j < 4; ++j)
        acc[i][j] = __builtin_amdgcn_mfma_f32_16x16x32_bf16(af[i], bfr[j], acc[i][j], 0, 0, 0);
  }
  float bcol[4];
#pragma unroll
  for (int nt = 0; nt < 4; ++nt) bcol[nt] = bias[n0 + wn0 + nt * 16 + lr];
#pragma unroll
  for (int mt = 0; mt < 4; ++mt)
#pragma unroll
    for (int nt = 0; nt < 4; ++nt) {
      const f32x4 c = acc[mt][nt];
      const int col = n0 + wn0 + nt * 16 + lr;
#pragma unroll
      for (int r = 0; r < 4; ++r) {
        const int row = m0 + wm0 + mt * 16 + lq * 4 + r;
        mid[(size_t)row * FF_ + col] = f2bf(gelu_f(c[r] + bcol[nt]));
      }
    }
}

// ------- FFN2 MFMA: y = h + midb @ W2b.T + b2 (fp32 out) --------------------
__global__ __launch_bounds__(256) void ffn2_mfma(const unsigned short* __restrict__ Ab,
    const unsigned short* __restrict__ Bb, const float* __restrict__ bias,
    const float* __restrict__ hres, float* __restrict__ y) {
  const int m0 = blockIdx.y * 128, n0 = blockIdx.x * 128;
  __shared__ __align__(16) unsigned short As[128 * 32];
  __shared__ __align__(16) unsigned short Bs[128 * 32];
  const int tid = threadIdx.x;
  const int s0 = tid, s1 = tid + 256;
  const int r0 = s0 >> 2, q0 = (s0 & 3) ^ ((r0 >> 1) & 3);
  const int r1 = s1 >> 2, q1 = (s1 & 3) ^ ((r1 >> 1) & 3);
  const unsigned short* aP0 = Ab + (size_t)(m0 + r0) * FF_ + q0 * 8;
  const unsigned short* aP1 = Ab + (size_t)(m0 + r1) * FF_ + q1 * 8;
  const unsigned short* bP0 = Bb + (size_t)(n0 + r0) * FF_ + q0 * 8;
  const unsigned short* bP1 = Bb + (size_t)(n0 + r1) * FF_ + q1 * 8;
  char* AsC = (char*)As;
  char* BsC = (char*)Bs;
  const int wave = tid >> 6, lane = tid & 63;
  const int wm0 = (wave >> 1) * 64, wn0 = (wave & 1) * 64;
  const int lr = lane & 15, lq = lane >> 4;
  int aoff[4], boff[4];
#pragma unroll
  for (int t = 0; t < 4; ++t) {
    aoff[t] = slot_of(wm0 + t * 16 + lr, lq) * 16;
    boff[t] = slot_of(wn0 + t * 16 + lr, lq) * 16;
  }
  f32x4 acc[4][4];
#pragma unroll
  for (int i = 0; i < 4; ++i)
#pragma unroll
    for (int j = 0; j < 4; ++j) acc[i][j] = (f32x4){0.f, 0.f, 0.f, 0.f};
  for (int kt = 0; kt < FF_; kt += 32) {
    __syncthreads();
    GLDS(aP0 + kt, AsC + s0 * 16);
    GLDS(aP1 + kt, AsC + s1 * 16);
    GLDS(bP0 + kt, BsC + s0 * 16);
    GLDS(bP1 + kt, BsC + s1 * 16);
    __syncthreads();
    bhalf8 af[4], bfr[4];
#pragma unroll
    for (int t = 0; t < 4; ++t) af[t] = *(const bhalf8*)(AsC + aoff[t]);
#pragma unroll
    for (int t = 0; t < 4; ++t) bfr[t] = *(const bhalf8*)(BsC + boff[t]);
#pragma unroll
    for (int i = 0; i < 4; ++i)
#pragma unroll
      for (int j = 0; j < 4; ++j)
        acc[i][j] = __builtin_amdgcn_mfma_f32_16x16x32_bf16(af[i], bfr[j], acc[i][j], 0, 0, 0);
  }
  float bcol[4];
#pragma unroll
  for (int nt = 0; nt < 4; ++nt) bcol[nt] = bias[n0 + wn0 + nt * 16 + lr];
#pragma unroll
  for (int mt = 0; mt < 4; ++mt)
#pragma unroll
    for (int nt = 0; nt < 4; ++nt) {
      const f32x4 c = acc[mt][nt];
      const int col = n0 + wn0 + nt * 16 + lr;
#pragma unroll
      for (int r = 0; r < 4; ++r) {
        const int row = m0 + wm0 + mt * 16 + lq * 4 + r;
        const size_t idx = (size_t)row * D_ + col;
        y[idx] = c[r] + bcol[nt] + hres[idx];
      }
    }
}

// ---------------- bf16 in-place a += b (8 elems/thread) ---------------------
__global__ __launch_bounds__(256) void add2b_kernel(unsigned short* __restrict__ a,
    const unsigned short* __restrict__ b) {
  const size_t i = (size_t)blockIdx.x * 256 + threadIdx.x;
  uint4 av = ((uint4*)a)[i];
  const uint4 bv = ((const uint4*)b)[i];
  av.x = addpair_bf(av.x, bv.x);
  av.y = addpair_bf(av.y, bv.y);
  av.z = addpair_bf(av.z, bv.z);
  av.w = addpair_bf(av.w, bv.w);
  ((uint4*)a)[i] = av;
}

// ---------------- Flash attention (bf16 in/out, fp32 VALU math) -------------
__global__ __launch_bounds__(256) void attn_kernel(const unsigned short* __restrict__ q,
    const unsigned short* __restrict__ k, const unsigned short* __restrict__ v,
    unsigned short* __restrict__ out) {
  const int bh = blockIdx.x;
  const int b = bh >> 4, h = bh & 15;
  const int q0 = blockIdx.y * 64;
  const int tid = threadIdx.x;
  const int tx = tid & 15, ty = tid >> 4;
  __shared__ __align__(16) float Qs[64][64];  // [d][r]
  __shared__ __align__(16) float Ks[64][64];  // [d][c]
  __shared__ __align__(16) float Vs[64][64];  // [kv][c]
  __shared__ __align__(16) float Ps[64][64];  // [r][c]
  {
    const int r = tid >> 2, d0 = (tid & 3) * 16;
    const unsigned short* src = q + ((size_t)(b * N_ + q0 + r)) * D_ + h * HD_ + d0;
#pragma unroll
    for (int half = 0; half < 2; ++half) {
      const uint4 u = *(const uint4*)(src + half * 8);
      const unsigned uu[4] = {u.x, u.y, u.z, u.w};
#pragma unroll
      for (int c = 0; c < 4; ++c) {
        Qs[d0 + half * 8 + 2 * c + 0][r] = b2f((unsigned short)(uu[c] & 0xffff)) * 0.125f;
        Qs[d0 + half * 8 + 2 * c + 1][r] = b2f((unsigned short)(uu[c] >> 16)) * 0.125f;
      }
    }
  }
  float m_i[4], l_i[4], o_acc[4][4];
#pragma unroll
  for (int i = 0; i < 4; ++i) {
    m_i[i] = -3.0e38f;
    l_i[i] = 0.f;
#pragma unroll
    for (int j = 0; j < 4; ++j) o_acc[i][j] = 0.f;
  }
  for (int kt = 0; kt < 16; ++kt) {
    __syncthreads();
    {
      const int r = tid >> 2, d0 = (tid & 3) * 16;
      const unsigned short* ks = k + ((size_t)(b * N_ + kt * 64 + r)) * D_ + h * HD_ + d0;
      const unsigned short* vs = v + ((size_t)(b * N_ + kt * 64 + r)) * D_ + h * HD_ + d0;
#pragma unroll
      for (int half = 0; half < 2; ++half) {
        const uint4 uk = *(const uint4*)(ks + half * 8);
        const uint4 uv = *(const uint4*)(vs + half * 8);
        const unsigned ku[4] = {uk.x, uk.y, uk.z, uk.w};
        const unsigned vu[4] = {uv.x, uv.y, uv.z, uv.w};
#pragma unroll
        for (int c = 0; c < 4; ++c) {
          Ks[d0 + half * 8 + 2 * c + 0][r] = b2f((unsigned short)(ku[c] & 0xffff));
          Ks[d0 + half * 8 + 2 * c + 1][r] = b2f((unsigned short)(ku[c] >> 16));
          Vs[r][d0 + half * 8 + 2 * c + 0] = b2f((unsigned short)(vu[c] & 0xffff));
          Vs[r][d0 + half * 8 + 2 * c + 1] = b2f((unsigned short)(vu[c] >> 16));
        }
      }
    }
    __syncthreads();
    float s[4][4] = {};
#pragma unroll 8
    for (int d = 0; d < 64; ++d) {
      const float4 av = *(const float4*)&Qs[d][ty * 4];
      const float4 bv = *(const float4*)&Ks[d][tx * 4];
      const float a_[4] = {av.x, av.y, av.z, av.w};
      const float b_[4] = {bv.x, bv.y, bv.z, bv.w};
#pragma unroll
      for (int i = 0; i < 4; ++i)
#pragma unroll
        for (int j = 0; j < 4; ++j) s[i][j] = fmaf(a_[i], b_[j], s[i][j]);
    }
    float alpha[4];
#pragma unroll
    for (int i = 0; i < 4; ++i) {
      float mt = fmaxf(fmaxf(s[i][0], s[i][1]), fmaxf(s[i][2], s[i][3]));
#pragma unroll
      for (int o = 8; o > 0; o >>= 1) mt = fmaxf(mt, __shfl_xor(mt, o));
      const float mn = fmaxf(m_i[i], mt);
      alpha[i] = __expf(m_i[i] - mn);
      m_i[i] = mn;
      float rsum = 0.f;
#pragma unroll
      for (int j = 0; j < 4; ++j) { s[i][j] = __expf(s[i][j] - mn); rsum += s[i][j]; }
#pragma unroll
      for (int o = 8; o > 0; o >>= 1) rsum += __shfl_xor(rsum, o);
      l_i[i] = l_i[i] * alpha[i] + rsum;
      Ps[ty * 4 + i][tx * 4 + 0] = s[i][0];
      Ps[ty * 4 + i][tx * 4 + 1] = s[i][1];
      Ps[ty * 4 + i][tx * 4 + 2] = s[i][2];
      Ps[ty * 4 + i][tx * 4 + 3] = s[i][3];
    }
    __syncthreads();
#pragma unroll
    for (int i = 0; i < 4; ++i)
#pragma unroll
      for (int j = 0; j < 4; ++j) o_acc[i][j] *= alpha[i];
#pragma unroll 8
    for (int d = 0; d < 64; ++d) {
      const float4 vv = *(const float4*)&Vs[d][tx * 4];
      const float v_[4] = {vv.x, vv.y, vv.z, vv.w};
      const float p0 = Ps[ty * 4 + 0][d];
      const float p1 = Ps[ty * 4 + 1][d];
      const float p2 = Ps[ty * 4 + 2][d];
      const float p3 = Ps[ty * 4 + 3][d];
#pragma unroll
      for (int j = 0; j < 4; ++j) {
        o_acc[0][j] = fmaf(p0, v_[j], o_acc[0][j]);
        o_acc[1][j] = fmaf(p1, v_[j], o_acc[1][j]);
        o_acc[2][j] = fmaf(p2, v_[j], o_acc[2][j]);
        o_acc[3][j] = fmaf(p3, v_[j], o_acc[3][j]);
      }
    }
  }
#pragma unroll
  for (int i = 0; i < 4; ++i) {
    const float inv = 1.f / l_i[i];
    ushort4 o4;
    o4.x = f2bf(o_acc[i][0] * inv);
    o4.y = f2bf(o_acc[i][1] * inv);
    o4.z = f2bf(o_acc[i][2] * inv);
    o4.w = f2bf(o_acc[i][3] * inv);
    *(ushort4*)(out + ((size_t)(b * N_ + q0 + ty * 4 + i)) * D_ + h * HD_ + tx * 4) = o4;
  }
}

// ---------------- load-balance scalar ---------------------------------------
__global__ void lb_kernel(const int* __restrict__ ecnt,
                          const float* __restrict__ psum, float* __restrict__ out) {
  if (threadIdx.x == 0 && blockIdx.x == 0) {
    float tot = 0.f;
    for (int e = 0; e < E_; ++e) tot += (float)ecnt[e];
    float s = 0.f;
    for (int e = 0; e < E_; ++e) s += (float)ecnt[e] / (tot + 1e-6f) * psum[e];
    out[0] = s * (float)E_;
  }
}

extern "C" void kernel_launch(void* const* d_in, const int* in_sizes, int n_in,
                              void* d_out, int out_size, void* d_ws, size_t ws_size,
                              hipStream_t stream) {
  (void)in_sizes; (void)n_in; (void)out_size; (void)ws_size;
  const float* x  = (const float*)d_in[0];
  const float* Wr = (const float*)d_in[1];
  const float* Wq = (const float*)d_in[2];
  const float* Wk = (const float*)d_in[3];
  const float* Wv = (const float*)d_in[4];
  const float* Wo = (const float*)d_in[5];
  const float* W1 = (const float*)d_in[6];
  const float* b1 = (const float*)d_in[7];
  const float* W2 = (const float*)d_in[8];
  const float* b2 = (const float*)d_in[9];
  const float* g1 = (const float*)d_in[10];
  const float* be1 = (const float*)d_in[11];
  const float* g2 = (const float*)d_in[12];
  const float* be2 = (const float*)d_in[13];
  float* y = (float*)d_out;

  // ---- workspace layout (bytes) -------------------------------------------
  char* p = (char*)d_ws;
  float* xn = (float*)p;                 p += SZ_ * 4;       // 16 MB fp32 LN1
  unsigned short* xnb = (unsigned short*)p;  p += SZ_ * 2;   // 8 MB bf16 LN1
  unsigned short* q2b = (unsigned short*)p;  p += 2 * SZ_ * 2;  // 16 MB [2][T][D]
  unsigned short* k2b = (unsigned short*)p;  p += 2 * SZ_ * 2;  // 16 MB
  unsigned short* v2b = (unsigned short*)p;  p += 2 * SZ_ * 2;  // 16 MB
  unsigned short* attb = (unsigned short*)p; p += SZ_ * 2;      // 8 MB
  unsigned short* W1b = (unsigned short*)p;  p += (size_t)FF_ * D_ * 2;  // 8 MB
  unsigned short* W2b = (unsigned short*)p;  p += (size_t)FF_ * D_ * 2;  // 8 MB
  float* psum = (float*)p;               p += E_ * 4;
  int* ecnt = (int*)p;                   p += E_ * 4;
  int* etok = (int*)p;                   p += (size_t)E_ * T_ * 4;
  float* ewt = (float*)p;                p += (size_t)E_ * T_ * 4;
  float* probs = (float*)p;              p += (size_t)T_ * E_ * 4;
  int* topi = (int*)p;                   p += T_ * 4;
  float2* topw = (float2*)p;
  // overlays (regions dead at time of reuse):
  unsigned short* o2b  = q2b;                 // o-proj 2 slots (q dead post-attn)
  float* hbuf          = (float*)k2b;         // h fp32 (k dead post-attn)
  unsigned short* hnb  = v2b;                 // hn bf16 (v dead post-attn)
  unsigned short* midb = (unsigned short*)d_ws;  // 32 MB over xn/xnb/q2b[0:8MB]

  // 1. LN1 (fp32 + bf16)
  ln_kernel<<<T_, 256, 0, stream>>>(x, g1, be1, xn, xnb);
  // 2. FFN weight conversion (independent)
  cvtw_kernel<<<(FF_ * D_) / 1024, 256, 0, stream>>>(W1, W1b);
  cvtw_kernel<<<(FF_ * D_) / 1024, 256, 0, stream>>>(W2, W2b);
  // 3. Router (fp32, deterministic)
  router_logits<<<T_, 256, 0, stream>>>(xn, Wr, probs, topi, topw);
  psum_kernel<<<1, 256, 0, stream>>>(probs, psum);
  build_lists<<<E_, 256, 0, stream>>>(topi, topw, ecnt, etok, ewt);
  // 4. MoE projections q,k,v (MFMA, gathered A, on-the-fly bf16 B)
  dim3 gmoe(D_ / 128, T_ / 128, E_);
  moe_mfma<<<gmoe, 256, 0, stream>>>(xnb, Wq, q2b, SZ_, ecnt, etok, ewt);
  moe_mfma<<<gmoe, 256, 0, stream>>>(xnb, Wk, k2b, SZ_, ecnt, etok, ewt);
  moe_mfma<<<gmoe, 256, 0, stream>>>(xnb, Wv, v2b, SZ_, ecnt, etok, ewt);
  // 5. Combine expert slots (bf16)
  add2b_kernel<<<SZ_ / 2048, 256, 0, stream>>>(q2b, q2b + SZ_);
  add2b_kernel<<<SZ_ / 2048, 256, 0, stream>>>(k2b, k2b + SZ_);
  add2b_kernel<<<SZ_ / 2048, 256, 0, stream>>>(v2b, v2b + SZ_);
  // 6. Attention (bf16 in/out)
  attn_kernel<<<dim3(B_ * H_, N_ / 64), 256, 0, stream>>>(q2b, k2b, v2b, attb);
  // 7. Output projection (2 slots into o2b)
  moe_mfma<<<gmoe, 256, 0, stream>>>(attb, Wo, o2b, SZ_, ecnt, etok, ewt);
  // 8. h = x + o0 + o1 ; hn = LN2(h)
  hln2_kernel<<<T_, 256, 0, stream>>>(x, o2b, o2b + SZ_, g2, be2, hbuf, hnb);
  // 9. FFN (MFMA)
  ffn1_mfma<<<dim3(FF_ / 128, T_ / 128), 256, 0, stream>>>(hnb, W1b, b1, midb);
  ffn2_mfma<<<dim3(D_ / 128, T_ / 128), 256, 0, stream>>>(midb, W2b, b2, hbuf, y);
  // 10. load-balance scalar
  lb_kernel<<<1, 64, 0, stream>>>(ecnt, psum, y + SZ_);
}